// Round 8
// baseline (517.499 us; speedup 1.0000x reference)
//
#include <hip/hip_runtime.h>

typedef __bf16 bf8 __attribute__((ext_vector_type(8)));
typedef float f4 __attribute__((ext_vector_type(4)));

__device__ __forceinline__ float b2f(unsigned short u) {
  union { unsigned int i; float f; } c; c.i = ((unsigned int)u) << 16; return c.f;
}
__device__ __forceinline__ unsigned short f2b(float f) {
  union { float f; unsigned int i; } c; c.f = f;
  unsigned int i = c.i;
  return (unsigned short)((i + 0x7FFFu + ((i >> 16) & 1u)) >> 16);  // RNE
}

// async global->LDS, 16 bytes per lane; LDS dest = wave-uniform base + lane*16
__device__ __forceinline__ void gl_lds16(const unsigned short* g, unsigned short* l) {
  __builtin_amdgcn_global_load_lds((const __attribute__((address_space(1))) unsigned int*)g,
                                   (__attribute__((address_space(3))) unsigned int*)l,
                                   16, 0, 0);
}

// cheap GELU (tanh form via sigmoid identity); |err| vs exact-erf GELU ~1e-3,
// below bf16 output rounding. Saturates correctly: v->+inf => v, v->-inf => 0.
__device__ __forceinline__ float gelu_fast(float v) {
  float w = v * v;
  float u = v * (-1.59576912f - 0.07135481f * w);  // = -2 * 0.79788456*(v + 0.044715 v^3)
  return v / (1.0f + __expf(u));
}

// ---------------- weight transpose+cast: f32 [K,N] -> bf16 [N,K] ----------------
__global__ void transpose_kernel(const float* __restrict__ in,
                                 unsigned short* __restrict__ out, int K, int N) {
  int idx = blockIdx.x * 256 + threadIdx.x;
  if (idx < K * N) {
    int n = idx / K, k = idx - n * K;
    out[idx] = f2b(in[k * N + n]);
  }
}

// ---------------- LayerNorm: C=192, one wave per token, f32 in -> bf16 out ----------------
__global__ __launch_bounds__(256) void ln_kernel(const float* __restrict__ xin,
                                                 const float* __restrict__ g,
                                                 const float* __restrict__ bb,
                                                 unsigned short* __restrict__ out) {
  long token = (long)blockIdx.x * 4 + (threadIdx.x >> 6);
  int lane = threadIdx.x & 63;
  const float* row = xin + token * 192;
  float v[3] = {row[lane], row[lane + 64], row[lane + 128]};
  float s = v[0] + v[1] + v[2];
#pragma unroll
  for (int m = 1; m < 64; m <<= 1) s += __shfl_xor(s, m, 64);
  float mean = s * (1.0f / 192.0f);
  float d0 = v[0] - mean, d1 = v[1] - mean, d2 = v[2] - mean;
  float dd = d0 * d0 + d1 * d1 + d2 * d2;
#pragma unroll
  for (int m = 1; m < 64; m <<= 1) dd += __shfl_xor(dd, m, 64);
  float rstd = rsqrtf(dd * (1.0f / 192.0f) + 1e-5f);
  unsigned short* orow = out + token * 192;
#pragma unroll
  for (int i = 0; i < 3; i++) {
    int c = lane + i * 64;
    orow[c] = f2b((v[i] - mean) * rstd * g[c] + bb[c]);
  }
}

// ---------------- MFMA GEMM: out = A[M,K](bf16) @ Bt[N,K]^T(bf16) + bias(f32) ----------------
// BM=128, BN=64, BK=64, 256 threads (4 waves), DEPTH-3 prefetch pipeline:
// 3 LDS buffers (72 KB -> 2 blocks/CU); iteration t issues tile t+2 into the
// buffer freed by the closing barrier of iteration t-1, then waits only tile
// t's 6 loads (s_waitcnt vmcnt(12)) — 12 loads stay in flight across TWO
// barrier periods, covering the ~1-2k cycle load latency that depth-1 missed.
// global_load_lds width-16 staging + XOR chunk swizzle (linear LDS dest,
// inverse-swizzled global source, swizzled ds_read).
// XCD-chunked tile remap for L2 locality (bijective when T%8==0).
template <int EPI>
__global__ __launch_bounds__(256) void gemm_kernel(const unsigned short* __restrict__ A,
                                                   const unsigned short* __restrict__ Bt,
                                                   const float* __restrict__ bias,
                                                   const float* __restrict__ res,
                                                   void* __restrict__ out, int K, int N) {
  __shared__ __align__(16) unsigned short As[3][128 * 64];  // 3 x 16 KiB
  __shared__ __align__(16) unsigned short Bs[3][64 * 64];   // 3 x  8 KiB
  const int tid = threadIdx.x;
  const int wave = tid >> 6;
  const int lane = tid & 63;
  const int quad = lane >> 4;
  const int l16 = lane & 15;

  const int NX = gridDim.x;
  int lin = blockIdx.y * NX + blockIdx.x;
  const int T = NX * gridDim.y;
  if ((T & 7) == 0) {
    lin = (lin & 7) * (T >> 3) + (lin >> 3);
  }
  const int bx = lin % NX;
  const int by = lin / NX;
  const long m0 = (long)by * 128;
  const long n0 = (long)bx * 64;

  // Per-lane staging source offsets (chunk = 16B = 8 shorts).
  // Linear LDS chunk L holds global chunk (row, cs^(row&7)).
  long a_src[4];
  int a_dstc[4];
#pragma unroll
  for (int j = 0; j < 4; ++j) {
    int L = (wave * 4 + j) * 64 + lane;
    int row = L >> 3, cs = L & 7;
    a_src[j] = (m0 + row) * (long)K + ((cs ^ (row & 7)) << 3);
    a_dstc[j] = (wave * 4 + j) * 512;  // shorts, wave-uniform
  }
  long b_src[2];
  int b_dstc[2];
#pragma unroll
  for (int j = 0; j < 2; ++j) {
    int L = (wave * 2 + j) * 64 + lane;
    int row = L >> 3, cs = L & 7;
    b_src[j] = (n0 + row) * (long)K + ((cs ^ (row & 7)) << 3);
    b_dstc[j] = (wave * 2 + j) * 512;
  }

  const int nT = K >> 6;  // >= 3 for all shapes here
  f4 acc[2][4] = {};

  // prologue: issue tiles 0 and 1 (oldest-first: tile0's 6 loads, then tile1's)
#pragma unroll
  for (int s = 0; s < 2; ++s) {
    const int k0 = s << 6;
#pragma unroll
    for (int j = 0; j < 4; ++j) gl_lds16(A + a_src[j] + k0, &As[s][a_dstc[j]]);
#pragma unroll
    for (int j = 0; j < 2; ++j) gl_lds16(Bt + b_src[j] + k0, &Bs[s][b_dstc[j]]);
  }

  int cur = 0;
  for (int t = 0; t < nT; ++t) {
    // issue tile t+2 into the buffer freed by iteration t-1's closing barrier
    if (t + 2 < nT) {
      const int k0 = (t + 2) << 6;
      int nb = cur + 2; if (nb >= 3) nb -= 3;
#pragma unroll
      for (int j = 0; j < 4; ++j) gl_lds16(A + a_src[j] + k0, &As[nb][a_dstc[j]]);
#pragma unroll
      for (int j = 0; j < 2; ++j) gl_lds16(Bt + b_src[j] + k0, &Bs[nb][b_dstc[j]]);
    }
    // wait only tile t's 6 loads; up to 12 newer loads stay in flight
    const int rem = nT - 1 - t;
    if (rem >= 2) {
      asm volatile("s_waitcnt vmcnt(12)" ::: "memory");
    } else if (rem == 1) {
      asm volatile("s_waitcnt vmcnt(6)" ::: "memory");
    } else {
      asm volatile("s_waitcnt vmcnt(0)" ::: "memory");
    }
    __builtin_amdgcn_s_barrier();          // all waves' tile-t stages landed
    __builtin_amdgcn_sched_barrier(0);     // fence: no ds_read hoisted above barrier
#pragma unroll
    for (int kk = 0; kk < 2; ++kk) {
      bf8 a[2], b[4];
#pragma unroll
      for (int mt = 0; mt < 2; ++mt) {
        int r = wave * 32 + mt * 16 + l16;
        int c = kk * 4 + quad;
        a[mt] = *(const bf8*)&As[cur][r * 64 + ((c ^ (r & 7)) << 3)];
      }
#pragma unroll
      for (int nt = 0; nt < 4; ++nt) {
        int r = nt * 16 + l16;
        int c = kk * 4 + quad;
        b[nt] = *(const bf8*)&Bs[cur][r * 64 + ((c ^ (r & 7)) << 3)];
      }
#pragma unroll
      for (int mt = 0; mt < 2; ++mt)
#pragma unroll
        for (int nt = 0; nt < 4; ++nt)
          acc[mt][nt] = __builtin_amdgcn_mfma_f32_16x16x32_bf16(a[mt], b[nt], acc[mt][nt], 0, 0, 0);
    }
    __builtin_amdgcn_sched_barrier(0);     // keep ds_reads above the end barrier
    __builtin_amdgcn_s_barrier();          // all waves done reading buf cur
    cur = (cur + 1 == 3) ? 0 : cur + 1;
  }

#pragma unroll
  for (int nt = 0; nt < 4; ++nt) {
    long n = n0 + nt * 16 + l16;
    float bv = bias[n];
#pragma unroll
    for (int mt = 0; mt < 2; ++mt) {
#pragma unroll
      for (int r = 0; r < 4; ++r) {
        long m = m0 + wave * 32 + mt * 16 + quad * 4 + r;
        float v = acc[mt][nt][r] + bv;
        long idx = m * N + n;
        if (EPI == 0) {
          ((unsigned short*)out)[idx] = f2b(v);
        } else if (EPI == 1) {
          ((float*)out)[idx] = v + res[idx];
        } else if (EPI == 2) {
          ((unsigned short*)out)[idx] = f2b(gelu_fast(v));
        } else {
          ((float*)out)[idx] = v + res[idx];
        }
      }
    }
  }
}

// ---------------- MFMA shifted-window attention ----------------
// Block = 128 threads = 2 waves; each wave owns one (b, wi, head).
// Q/K are loaded DIRECTLY global->register as MFMA fragments (lane=token-row,
// vector=8 dims) — no LDS staging. LDS per wave (shorts): Vt[32x72]@0,
// P[64x72]@2304, total 6912 (~30 KB/block -> 5 blocks/CU, 10 waves/CU).
__global__ __launch_bounds__(128) void attn_kernel(const unsigned short* __restrict__ qkv,  // [B*3136,576] bf16
                                                   const float* __restrict__ rel_t,         // [169,6] f32
                                                   unsigned short* __restrict__ o) {        // [B*3136,192] bf16
  __shared__ __align__(16) unsigned short sh[2 * 6912];
  __shared__ float relh[2][170];
  __shared__ int toksh[2][49];
  __shared__ int zsh[2][49];
  const int wave = threadIdx.x >> 6;
  const int lane = threadIdx.x & 63;
  const int quad = lane >> 4;
  const int l16 = lane & 15;
  const int p = blockIdx.x * 2 + wave;  // 0..12287
  const int head = p % 6;
  const int wib = p / 6;
  const int wi = wib & 63;
  const int b = wib >> 6;
  unsigned short* Vts = sh + wave * 6912;   // stride 72 (32 dims x 64 tokens)
  unsigned short* Ps = Vts + 2304;          // stride 72

  // token map + zone codes (zones in SHIFTED-frame position, per Swin img_mask construction)
  if (lane < 49) {
    int r = lane / 7, c = lane - (lane / 7) * 7;
    int ph = (wi >> 3) * 7 + r, pw = (wi & 7) * 7 + c;
    int h = ph + 3; if (h >= 56) h -= 56;
    int w = pw + 3; if (w >= 56) w -= 56;
    toksh[wave][lane] = (b * 56 + h) * 56 + w;
    int zh = (ph < 49) ? 0 : (ph < 53 ? 1 : 2);
    int zw = (pw < 49) ? 0 : (pw < 53 ? 1 : 2);
    zsh[wave][lane] = zh * 3 + zw;
  }
  // rel_table column for this head -> LDS (169 floats)
  for (int i = lane; i < 169; i += 64) relh[wave][i] = rel_t[i * 6 + head];
  // zero Vt token-cols 48..63
  {
#pragma unroll
    for (int e = 0; e < 4; e++) {
      int ee = lane + e * 64;  // 0..255
      int d = ee >> 3, c8 = ee & 7;
      *(unsigned int*)&Vts[d * 72 + 48 + c8 * 2] = 0u;  // max 31*72+62=2294 < 2304
    }
  }
  __syncthreads();

  // stage Vt only (49 tokens x 32 dims, transpose to [dim][token])
  for (int e = lane; e < 196; e += 64) {
    int n = e >> 2, c = e & 3;
    int t = toksh[wave][n];
    uint4 vc = *(const uint4*)(qkv + (long)t * 576 + head * 32 + 384 + c * 8);
    const unsigned short* vv = (const unsigned short*)&vc;
#pragma unroll
    for (int j = 0; j < 8; j++) Vts[(c * 8 + j) * 72 + n] = vv[j];
  }

  // Q/K fragments direct from global: lane l16 = token-row, quad*8 = dim chunk
  bf8 zv;
#pragma unroll
  for (int q8 = 0; q8 < 8; q8++) zv[q8] = (__bf16)0.0f;
  bf8 af[4], bf_[4];
#pragma unroll
  for (int i = 0; i < 4; i++) {
    int row = 16 * i + l16;
    int rv = row < 49 ? row : 48;
    long base = (long)toksh[wave][rv] * 576 + head * 32 + quad * 8;
    bf8 qf = *(const bf8*)(qkv + base);
    bf8 kf = *(const bf8*)(qkv + base + 192);
    if (row >= 49) { qf = zv; kf = zv; }
    af[i] = qf;
    bf_[i] = kf;
  }

  // S = Q @ K^T  (16 MFMAs, K=32 exact)
  f4 S[4][4];
#pragma unroll
  for (int i = 0; i < 4; i++)
#pragma unroll
    for (int j = 0; j < 4; j++)
      S[i][j] = __builtin_amdgcn_mfma_f32_16x16x32_bf16(af[i], bf_[j], (f4){0.f, 0.f, 0.f, 0.f}, 0, 0, 0);

  // per-lane column attributes
  int colv[4], colkey[4], zcol[4];
#pragma unroll
  for (int jt = 0; jt < 4; jt++) {
    int col = 16 * jt + l16;
    int cc = col < 49 ? col : 48;
    int rj = cc / 7, cj = cc - rj * 7;
    colkey[jt] = rj * 13 + cj;
    zcol[jt] = zsh[wave][cc];
    colv[jt] = (col < 49);
  }

  __syncthreads();  // Vt staged (needed before PV below); also covers Ps reuse

  // scale + analytic bias/mask + in-register softmax -> P (bf16) in LDS
  const float sc = 0.17677669529663687f;  // 1/sqrt(32)
#pragma unroll
  for (int it = 0; it < 4; it++) {
#pragma unroll
    for (int r = 0; r < 4; r++) {
      int row = 16 * it + quad * 4 + r;
      int row2 = row < 49 ? row : 48;
      int ri = row2 / 7, ci = row2 - ri * 7;
      int rk = ri * 13 + ci + 84;
      int zr = zsh[wave][row2];
      float v[4];
#pragma unroll
      for (int jt = 0; jt < 4; jt++) {
        float bias = relh[wave][rk - colkey[jt]];
        float msk = (zr == zcol[jt]) ? 0.0f : -100.0f;
        float val = S[it][jt][r] * sc + bias + msk;
        v[jt] = colv[jt] ? val : -1e30f;
      }
      float mx = fmaxf(fmaxf(v[0], v[1]), fmaxf(v[2], v[3]));
#pragma unroll
      for (int m = 1; m < 16; m <<= 1) mx = fmaxf(mx, __shfl_xor(mx, m, 64));
      float e0 = __expf(v[0] - mx), e1 = __expf(v[1] - mx), e2 = __expf(v[2] - mx), e3 = __expf(v[3] - mx);
      float sum = e0 + e1 + e2 + e3;
#pragma unroll
      for (int m = 1; m < 16; m <<= 1) sum += __shfl_xor(sum, m, 64);
      float inv = 1.0f / sum;
      Ps[row * 72 + 0 + l16] = f2b(e0 * inv);
      Ps[row * 72 + 16 + l16] = f2b(e1 * inv);
      Ps[row * 72 + 32 + l16] = f2b(e2 * inv);
      Ps[row * 72 + 48 + l16] = f2b(e3 * inv);
    }
  }
  __syncthreads();

  // O = P @ V   (P: 64x64 A-operand, Vt: V^T as B-operand, 16 MFMAs)
  f4 O[4][2] = {};
#pragma unroll
  for (int ks = 0; ks < 2; ks++) {
    bf8 pv[2];
#pragma unroll
    for (int nt = 0; nt < 2; nt++) pv[nt] = *(const bf8*)&Vts[(16 * nt + l16) * 72 + ks * 32 + quad * 8];
#pragma unroll
    for (int mt = 0; mt < 4; mt++) {
      bf8 pa = *(const bf8*)&Ps[(16 * mt + l16) * 72 + ks * 32 + quad * 8];
#pragma unroll
      for (int nt = 0; nt < 2; nt++)
        O[mt][nt] = __builtin_amdgcn_mfma_f32_16x16x32_bf16(pa, pv[nt], O[mt][nt], 0, 0, 0);
    }
  }
  // store
#pragma unroll
  for (int mt = 0; mt < 4; mt++) {
#pragma unroll
    for (int r = 0; r < 4; r++) {
      int row = 16 * mt + quad * 4 + r;
      if (row < 49) {
        long base = (long)toksh[wave][row] * 192 + head * 32 + l16;
        o[base] = f2b(O[mt][0][r]);
        o[base + 16] = f2b(O[mt][1][r]);
      }
    }
  }
}

extern "C" void kernel_launch(void* const* d_in, const int* in_sizes, int n_in,
                              void* d_out, int out_size, void* d_ws, size_t ws_size,
                              hipStream_t stream) {
  const float* x      = (const float*)d_in[0];
  const float* n1g    = (const float*)d_in[1];
  const float* n1b    = (const float*)d_in[2];
  const float* qkv_w  = (const float*)d_in[3];
  const float* qkv_b  = (const float*)d_in[4];
  const float* proj_w = (const float*)d_in[5];
  const float* proj_b = (const float*)d_in[6];
  const float* n2g    = (const float*)d_in[7];
  const float* n2b    = (const float*)d_in[8];
  const float* fc1_w  = (const float*)d_in[9];
  const float* fc1_b  = (const float*)d_in[10];
  const float* fc2_w  = (const float*)d_in[11];
  const float* fc2_b  = (const float*)d_in[12];
  const float* rel_t  = (const float*)d_in[13];
  const float* mask   = (const float*)d_in[15];
  (void)mask;

  char* ws = (char*)d_ws;
  unsigned short* qkv_wT  = (unsigned short*)(ws + 0);          // 576x192 bf16
  unsigned short* proj_wT = (unsigned short*)(ws + 221184);     // 192x192
  unsigned short* fc1_wT  = (unsigned short*)(ws + 294912);     // 768x192
  unsigned short* fc2_wT  = (unsigned short*)(ws + 589824);     // 192x768
  unsigned short* bufA    = (unsigned short*)(ws + 884736);     // 100352x192 bf16
  unsigned short* bufB    = (unsigned short*)(ws + 39419904ULL);// 100352x576/768 bf16
  float*          xres    = (float*)(ws + 193560576ULL);        // 100352x192 f32

  const int M = 100352;  // 32 * 56 * 56

  transpose_kernel<<<(192 * 576 + 255) / 256, 256, 0, stream>>>(qkv_w, qkv_wT, 192, 576);
  transpose_kernel<<<(192 * 192 + 255) / 256, 256, 0, stream>>>(proj_w, proj_wT, 192, 192);
  transpose_kernel<<<(192 * 768 + 255) / 256, 256, 0, stream>>>(fc1_w, fc1_wT, 192, 768);
  transpose_kernel<<<(768 * 192 + 255) / 256, 256, 0, stream>>>(fc2_w, fc2_wT, 768, 192);

  ln_kernel<<<M / 4, 256, 0, stream>>>(x, n1g, n1b, bufA);
  gemm_kernel<0><<<dim3(576 / 64, M / 128), 256, 0, stream>>>(bufA, qkv_wT, qkv_b, nullptr, bufB, 192, 576);
  attn_kernel<<<12288 / 2, 128, 0, stream>>>(bufB, rel_t, bufA);
  gemm_kernel<1><<<dim3(192 / 64, M / 128), 256, 0, stream>>>(bufA, proj_wT, proj_b, x, xres, 192, 192);
  ln_kernel<<<M / 4, 256, 0, stream>>>(xres, n2g, n2b, bufA);
  gemm_kernel<2><<<dim3(768 / 64, M / 128), 256, 0, stream>>>(bufA, fc1_wT, fc1_b, nullptr, bufB, 192, 768);
  gemm_kernel<3><<<dim3(192 / 64, M / 128), 256, 0, stream>>>(bufB, fc2_wT, fc2_b, xres, d_out, 768, 192);
}

// Round 9
// 504.628 us; speedup vs baseline: 1.0255x; 1.0255x over previous
//
#include <hip/hip_runtime.h>

typedef __bf16 bf8 __attribute__((ext_vector_type(8)));
typedef float f4 __attribute__((ext_vector_type(4)));

// native bf16 store (compiler emits v_cvt_pk_bf16_f32 / single-op converts; RNE)
__device__ __forceinline__ void stb(unsigned short* p, float v) { *(__bf16*)p = (__bf16)v; }

// async global->LDS, 16 bytes per lane; LDS dest = wave-uniform base + lane*16
__device__ __forceinline__ void gl_lds16(const unsigned short* g, unsigned short* l) {
  __builtin_amdgcn_global_load_lds((const __attribute__((address_space(1))) unsigned int*)g,
                                   (__attribute__((address_space(3))) unsigned int*)l,
                                   16, 0, 0);
}

// cheap GELU (tanh form via sigmoid identity); |err| vs exact-erf GELU ~1e-3,
// below bf16 output rounding. Saturates correctly: v->+inf => v, v->-inf => 0.
__device__ __forceinline__ float gelu_fast(float v) {
  float w = v * v;
  float u = v * (-1.59576912f - 0.07135481f * w);
  return v / (1.0f + __expf(u));
}

// ---------------- weight transpose+cast: f32 [K,N] -> bf16 [N,K] ----------------
__global__ void transpose_kernel(const float* __restrict__ in,
                                 unsigned short* __restrict__ out, int K, int N) {
  int idx = blockIdx.x * 256 + threadIdx.x;
  if (idx < K * N) {
    int n = idx / K, k = idx - n * K;
    stb(&out[idx], in[k * N + n]);
  }
}

// ---------------- LayerNorm: C=192, one wave per token, f32 in -> bf16 out ----------------
__global__ __launch_bounds__(256) void ln_kernel(const float* __restrict__ xin,
                                                 const float* __restrict__ g,
                                                 const float* __restrict__ bb,
                                                 unsigned short* __restrict__ out) {
  long token = (long)blockIdx.x * 4 + (threadIdx.x >> 6);
  int lane = threadIdx.x & 63;
  const float* row = xin + token * 192;
  float v[3] = {row[lane], row[lane + 64], row[lane + 128]};
  float s = v[0] + v[1] + v[2];
#pragma unroll
  for (int m = 1; m < 64; m <<= 1) s += __shfl_xor(s, m, 64);
  float mean = s * (1.0f / 192.0f);
  float d0 = v[0] - mean, d1 = v[1] - mean, d2 = v[2] - mean;
  float dd = d0 * d0 + d1 * d1 + d2 * d2;
#pragma unroll
  for (int m = 1; m < 64; m <<= 1) dd += __shfl_xor(dd, m, 64);
  float rstd = rsqrtf(dd * (1.0f / 192.0f) + 1e-5f);
  unsigned short* orow = out + token * 192;
#pragma unroll
  for (int i = 0; i < 3; i++) {
    int c = lane + i * 64;
    stb(&orow[c], (v[i] - mean) * rstd * g[c] + bb[c]);
  }
}

// ---------------- MFMA GEMM: out = A[M,K](bf16) @ Bt[N,K]^T(bf16) + bias(f32) ----------------
// BM=128, BN=64, BK=64, 256 threads (4 waves), double-buffered LDS,
// global_load_lds width-16 staging + XOR chunk swizzle, counted vmcnt(6),
// XCD-chunked tile remap (round-6 structure, best measured).
template <int EPI>
__global__ __launch_bounds__(256) void gemm_kernel(const unsigned short* __restrict__ A,
                                                   const unsigned short* __restrict__ Bt,
                                                   const float* __restrict__ bias,
                                                   const float* __restrict__ res,
                                                   void* __restrict__ out, int K, int N) {
  __shared__ __align__(16) unsigned short As[2][128 * 64];  // 2 x 16 KiB
  __shared__ __align__(16) unsigned short Bs[2][64 * 64];   // 2 x  8 KiB
  const int tid = threadIdx.x;
  const int wave = tid >> 6;
  const int lane = tid & 63;
  const int quad = lane >> 4;
  const int l16 = lane & 15;

  const int NX = gridDim.x;
  int lin = blockIdx.y * NX + blockIdx.x;
  const int T = NX * gridDim.y;
  if ((T & 7) == 0) {
    lin = (lin & 7) * (T >> 3) + (lin >> 3);
  }
  const int bx = lin % NX;
  const int by = lin / NX;
  const long m0 = (long)by * 128;
  const long n0 = (long)bx * 64;

  long a_src[4];
  int a_dstc[4];
#pragma unroll
  for (int j = 0; j < 4; ++j) {
    int L = (wave * 4 + j) * 64 + lane;
    int row = L >> 3, cs = L & 7;
    a_src[j] = (m0 + row) * (long)K + ((cs ^ (row & 7)) << 3);
    a_dstc[j] = (wave * 4 + j) * 512;
  }
  long b_src[2];
  int b_dstc[2];
#pragma unroll
  for (int j = 0; j < 2; ++j) {
    int L = (wave * 2 + j) * 64 + lane;
    int row = L >> 3, cs = L & 7;
    b_src[j] = (n0 + row) * (long)K + ((cs ^ (row & 7)) << 3);
    b_dstc[j] = (wave * 2 + j) * 512;
  }

  const int nT = K >> 6;
  f4 acc[2][4] = {};

#pragma unroll
  for (int j = 0; j < 4; ++j) gl_lds16(A + a_src[j], &As[0][a_dstc[j]]);
#pragma unroll
  for (int j = 0; j < 2; ++j) gl_lds16(Bt + b_src[j], &Bs[0][b_dstc[j]]);

  int cur = 0;
  for (int t = 0; t < nT; ++t) {
    if (t + 1 < nT) {
      const int k0 = (t + 1) << 6;
#pragma unroll
      for (int j = 0; j < 4; ++j) gl_lds16(A + a_src[j] + k0, &As[cur ^ 1][a_dstc[j]]);
#pragma unroll
      for (int j = 0; j < 2; ++j) gl_lds16(Bt + b_src[j] + k0, &Bs[cur ^ 1][b_dstc[j]]);
      asm volatile("s_waitcnt vmcnt(6)" ::: "memory");
    } else {
      asm volatile("s_waitcnt vmcnt(0)" ::: "memory");
    }
    __builtin_amdgcn_s_barrier();
    __builtin_amdgcn_sched_barrier(0);
#pragma unroll
    for (int kk = 0; kk < 2; ++kk) {
      bf8 a[2], b[4];
#pragma unroll
      for (int mt = 0; mt < 2; ++mt) {
        int r = wave * 32 + mt * 16 + l16;
        int c = kk * 4 + quad;
        a[mt] = *(const bf8*)&As[cur][r * 64 + ((c ^ (r & 7)) << 3)];
      }
#pragma unroll
      for (int nt = 0; nt < 4; ++nt) {
        int r = nt * 16 + l16;
        int c = kk * 4 + quad;
        b[nt] = *(const bf8*)&Bs[cur][r * 64 + ((c ^ (r & 7)) << 3)];
      }
#pragma unroll
      for (int mt = 0; mt < 2; ++mt)
#pragma unroll
        for (int nt = 0; nt < 4; ++nt)
          acc[mt][nt] = __builtin_amdgcn_mfma_f32_16x16x32_bf16(a[mt], b[nt], acc[mt][nt], 0, 0, 0);
    }
    __builtin_amdgcn_sched_barrier(0);
    __builtin_amdgcn_s_barrier();
    cur ^= 1;
  }

#pragma unroll
  for (int nt = 0; nt < 4; ++nt) {
    long n = n0 + nt * 16 + l16;
    float bv = bias[n];
#pragma unroll
    for (int mt = 0; mt < 2; ++mt) {
#pragma unroll
      for (int r = 0; r < 4; ++r) {
        long m = m0 + wave * 32 + mt * 16 + quad * 4 + r;
        float v = acc[mt][nt][r] + bv;
        long idx = m * N + n;
        if (EPI == 0) {
          stb(&((unsigned short*)out)[idx], v);
        } else if (EPI == 2) {
          stb(&((unsigned short*)out)[idx], gelu_fast(v));
        } else {
          ((float*)out)[idx] = v + res[idx];
        }
      }
    }
  }
}

// ---------------- fused proj GEMM + residual + LayerNorm2 ----------------
// BM=128, BN=192 (full row), BK=64, K=192, 256 threads (4 waves), grid (1, 784).
// LDS exactly 80 KiB (2x16K A + 2x24K B) -> 2 blocks/CU. Each block owns rows
// [m0,m0+128) exclusively (NX=1) -> in-place LN write into the A buffer is safe.
// Epilogue: v = acc + proj_b + x  -> xres (f32);  LN(v) -> lnout (bf16, = A buf).
__global__ __launch_bounds__(256) void proj_ln_kernel(const unsigned short* __restrict__ A,
                                                      const unsigned short* __restrict__ Bt,
                                                      const float* __restrict__ bias,
                                                      const float* __restrict__ res,
                                                      const float* __restrict__ g2,
                                                      const float* __restrict__ b2,
                                                      float* __restrict__ xres,
                                                      unsigned short* __restrict__ lnout) {
  __shared__ __align__(16) unsigned short As[2][128 * 64];  // 32 KiB
  __shared__ __align__(16) unsigned short Bs[2][192 * 64];  // 48 KiB
  const int tid = threadIdx.x;
  const int wave = tid >> 6;
  const int lane = tid & 63;
  const int quad = lane >> 4;
  const int l16 = lane & 15;

  int lin = blockIdx.y;
  const int T = gridDim.y;
  if ((T & 7) == 0) lin = (lin & 7) * (T >> 3) + (lin >> 3);
  const long m0 = (long)lin * 128;

  long a_src[4];
  int a_dstc[4];
#pragma unroll
  for (int j = 0; j < 4; ++j) {
    int L = (wave * 4 + j) * 64 + lane;
    int row = L >> 3, cs = L & 7;
    a_src[j] = (m0 + row) * 192L + ((cs ^ (row & 7)) << 3);
    a_dstc[j] = (wave * 4 + j) * 512;
  }
  long b_src[6];
  int b_dstc[6];
#pragma unroll
  for (int j = 0; j < 6; ++j) {
    int L = (wave * 6 + j) * 64 + lane;
    int row = L >> 3, cs = L & 7;
    b_src[j] = row * 192L + ((cs ^ (row & 7)) << 3);
    b_dstc[j] = (wave * 6 + j) * 512;
  }

  f4 acc[2][12] = {};

  // prologue: stage tile 0 (10 loads/wave)
#pragma unroll
  for (int j = 0; j < 4; ++j) gl_lds16(A + a_src[j], &As[0][a_dstc[j]]);
#pragma unroll
  for (int j = 0; j < 6; ++j) gl_lds16(Bt + b_src[j], &Bs[0][b_dstc[j]]);

  int cur = 0;
  for (int t = 0; t < 3; ++t) {
    if (t + 1 < 3) {
      const int k0 = (t + 1) << 6;
#pragma unroll
      for (int j = 0; j < 4; ++j) gl_lds16(A + a_src[j] + k0, &As[cur ^ 1][a_dstc[j]]);
#pragma unroll
      for (int j = 0; j < 6; ++j) gl_lds16(Bt + b_src[j] + k0, &Bs[cur ^ 1][b_dstc[j]]);
      asm volatile("s_waitcnt vmcnt(10)" ::: "memory");
    } else {
      asm volatile("s_waitcnt vmcnt(0)" ::: "memory");
    }
    __builtin_amdgcn_s_barrier();
    __builtin_amdgcn_sched_barrier(0);
#pragma unroll
    for (int kk = 0; kk < 2; ++kk) {
      bf8 a[2];
#pragma unroll
      for (int mt = 0; mt < 2; ++mt) {
        int r = wave * 32 + mt * 16 + l16;
        int c = kk * 4 + quad;
        a[mt] = *(const bf8*)&As[cur][r * 64 + ((c ^ (r & 7)) << 3)];
      }
#pragma unroll
      for (int nt = 0; nt < 12; ++nt) {
        int r = nt * 16 + l16;
        int c = kk * 4 + quad;
        bf8 b = *(const bf8*)&Bs[cur][r * 64 + ((c ^ (r & 7)) << 3)];
#pragma unroll
        for (int mt = 0; mt < 2; ++mt)
          acc[mt][nt] = __builtin_amdgcn_mfma_f32_16x16x32_bf16(a[mt], b, acc[mt][nt], 0, 0, 0);
      }
    }
    __builtin_amdgcn_sched_barrier(0);
    __builtin_amdgcn_s_barrier();
    cur ^= 1;
  }

  // epilogue: residual add -> xres; full-row LN (16 lanes share a row) -> lnout
#pragma unroll
  for (int mt = 0; mt < 2; ++mt) {
#pragma unroll
    for (int r = 0; r < 4; ++r) {
      long mm = m0 + wave * 32 + mt * 16 + quad * 4 + r;
      const float* rrow = res + mm * 192;
      float v[12];
      float s = 0.0f;
#pragma unroll
      for (int nt = 0; nt < 12; ++nt) {
        int n = nt * 16 + l16;
        float t = acc[mt][nt][r] + bias[n] + rrow[n];
        v[nt] = t;
        s += t;
      }
#pragma unroll
      for (int m = 1; m < 16; m <<= 1) s += __shfl_xor(s, m, 64);
      float mean = s * (1.0f / 192.0f);
      float d = 0.0f;
#pragma unroll
      for (int nt = 0; nt < 12; ++nt) {
        float dd = v[nt] - mean;
        d += dd * dd;
      }
#pragma unroll
      for (int m = 1; m < 16; m <<= 1) d += __shfl_xor(d, m, 64);
      float rstd = rsqrtf(d * (1.0f / 192.0f) + 1e-5f);
      float* xrow = xres + mm * 192;
      unsigned short* lrow = lnout + mm * 192;
#pragma unroll
      for (int nt = 0; nt < 12; ++nt) {
        int n = nt * 16 + l16;
        xrow[n] = v[nt];
        stb(&lrow[n], (v[nt] - mean) * rstd * g2[n] + b2[n]);
      }
    }
  }
}

// ---------------- MFMA shifted-window attention ----------------
// Block = 128 threads = 2 waves; each wave owns one (b, wi, head).
// Q/K direct global->register fragments; LDS per wave: Vt[32x72] + P[64x72].
__global__ __launch_bounds__(128) void attn_kernel(const unsigned short* __restrict__ qkv,  // [B*3136,576] bf16
                                                   const float* __restrict__ rel_t,         // [169,6] f32
                                                   unsigned short* __restrict__ o) {        // [B*3136,192] bf16
  __shared__ __align__(16) unsigned short sh[2 * 6912];
  __shared__ float relh[2][170];
  __shared__ int toksh[2][49];
  __shared__ int zsh[2][49];
  const int wave = threadIdx.x >> 6;
  const int lane = threadIdx.x & 63;
  const int quad = lane >> 4;
  const int l16 = lane & 15;
  const int p = blockIdx.x * 2 + wave;
  const int head = p % 6;
  const int wib = p / 6;
  const int wi = wib & 63;
  const int b = wib >> 6;
  unsigned short* Vts = sh + wave * 6912;
  unsigned short* Ps = Vts + 2304;

  if (lane < 49) {
    int r = lane / 7, c = lane - (lane / 7) * 7;
    int ph = (wi >> 3) * 7 + r, pw = (wi & 7) * 7 + c;
    int h = ph + 3; if (h >= 56) h -= 56;
    int w = pw + 3; if (w >= 56) w -= 56;
    toksh[wave][lane] = (b * 56 + h) * 56 + w;
    int zh = (ph < 49) ? 0 : (ph < 53 ? 1 : 2);
    int zw = (pw < 49) ? 0 : (pw < 53 ? 1 : 2);
    zsh[wave][lane] = zh * 3 + zw;
  }
  for (int i = lane; i < 169; i += 64) relh[wave][i] = rel_t[i * 6 + head];
  {
#pragma unroll
    for (int e = 0; e < 4; e++) {
      int ee = lane + e * 64;
      int d = ee >> 3, c8 = ee & 7;
      *(unsigned int*)&Vts[d * 72 + 48 + c8 * 2] = 0u;
    }
  }
  __syncthreads();

  for (int e = lane; e < 196; e += 64) {
    int n = e >> 2, c = e & 3;
    int t = toksh[wave][n];
    uint4 vc = *(const uint4*)(qkv + (long)t * 576 + head * 32 + 384 + c * 8);
    const unsigned short* vv = (const unsigned short*)&vc;
#pragma unroll
    for (int j = 0; j < 8; j++) Vts[(c * 8 + j) * 72 + n] = vv[j];
  }

  bf8 zv;
#pragma unroll
  for (int q8 = 0; q8 < 8; q8++) zv[q8] = (__bf16)0.0f;
  bf8 af[4], bf_[4];
#pragma unroll
  for (int i = 0; i < 4; i++) {
    int row = 16 * i + l16;
    int rv = row < 49 ? row : 48;
    long base = (long)toksh[wave][rv] * 576 + head * 32 + quad * 8;
    bf8 qf = *(const bf8*)(qkv + base);
    bf8 kf = *(const bf8*)(qkv + base + 192);
    if (row >= 49) { qf = zv; kf = zv; }
    af[i] = qf;
    bf_[i] = kf;
  }

  f4 S[4][4];
#pragma unroll
  for (int i = 0; i < 4; i++)
#pragma unroll
    for (int j = 0; j < 4; j++)
      S[i][j] = __builtin_amdgcn_mfma_f32_16x16x32_bf16(af[i], bf_[j], (f4){0.f, 0.f, 0.f, 0.f}, 0, 0, 0);

  int colv[4], colkey[4], zcol[4];
#pragma unroll
  for (int jt = 0; jt < 4; jt++) {
    int col = 16 * jt + l16;
    int cc = col < 49 ? col : 48;
    int rj = cc / 7, cj = cc - rj * 7;
    colkey[jt] = rj * 13 + cj;
    zcol[jt] = zsh[wave][cc];
    colv[jt] = (col < 49);
  }

  __syncthreads();

  const float sc = 0.17677669529663687f;  // 1/sqrt(32)
#pragma unroll
  for (int it = 0; it < 4; it++) {
#pragma unroll
    for (int r = 0; r < 4; r++) {
      int row = 16 * it + quad * 4 + r;
      int row2 = row < 49 ? row : 48;
      int ri = row2 / 7, ci = row2 - ri * 7;
      int rk = ri * 13 + ci + 84;
      int zr = zsh[wave][row2];
      float v[4];
#pragma unroll
      for (int jt = 0; jt < 4; jt++) {
        float bias = relh[wave][rk - colkey[jt]];
        float msk = (zr == zcol[jt]) ? 0.0f : -100.0f;
        float val = S[it][jt][r] * sc + bias + msk;
        v[jt] = colv[jt] ? val : -1e30f;
      }
      float mx = fmaxf(fmaxf(v[0], v[1]), fmaxf(v[2], v[3]));
#pragma unroll
      for (int m = 1; m < 16; m <<= 1) mx = fmaxf(mx, __shfl_xor(mx, m, 64));
      float e0 = __expf(v[0] - mx), e1 = __expf(v[1] - mx), e2 = __expf(v[2] - mx), e3 = __expf(v[3] - mx);
      float sum = e0 + e1 + e2 + e3;
#pragma unroll
      for (int m = 1; m < 16; m <<= 1) sum += __shfl_xor(sum, m, 64);
      float inv = 1.0f / sum;
      stb(&Ps[row * 72 + 0 + l16], e0 * inv);
      stb(&Ps[row * 72 + 16 + l16], e1 * inv);
      stb(&Ps[row * 72 + 32 + l16], e2 * inv);
      stb(&Ps[row * 72 + 48 + l16], e3 * inv);
    }
  }
  __syncthreads();

  f4 O[4][2] = {};
#pragma unroll
  for (int ks = 0; ks < 2; ks++) {
    bf8 pv[2];
#pragma unroll
    for (int nt = 0; nt < 2; nt++) pv[nt] = *(const bf8*)&Vts[(16 * nt + l16) * 72 + ks * 32 + quad * 8];
#pragma unroll
    for (int mt = 0; mt < 4; mt++) {
      bf8 pa = *(const bf8*)&Ps[(16 * mt + l16) * 72 + ks * 32 + quad * 8];
#pragma unroll
      for (int nt = 0; nt < 2; nt++)
        O[mt][nt] = __builtin_amdgcn_mfma_f32_16x16x32_bf16(pa, pv[nt], O[mt][nt], 0, 0, 0);
    }
  }
#pragma unroll
  for (int mt = 0; mt < 4; mt++) {
#pragma unroll
    for (int r = 0; r < 4; r++) {
      int row = 16 * mt + quad * 4 + r;
      if (row < 49) {
        long base = (long)toksh[wave][row] * 192 + head * 32 + l16;
        stb(&o[base], O[mt][0][r]);
        stb(&o[base + 16], O[mt][1][r]);
      }
    }
  }
}

extern "C" void kernel_launch(void* const* d_in, const int* in_sizes, int n_in,
                              void* d_out, int out_size, void* d_ws, size_t ws_size,
                              hipStream_t stream) {
  const float* x      = (const float*)d_in[0];
  const float* n1g    = (const float*)d_in[1];
  const float* n1b    = (const float*)d_in[2];
  const float* qkv_w  = (const float*)d_in[3];
  const float* qkv_b  = (const float*)d_in[4];
  const float* proj_w = (const float*)d_in[5];
  const float* proj_b = (const float*)d_in[6];
  const float* n2g    = (const float*)d_in[7];
  const float* n2b    = (const float*)d_in[8];
  const float* fc1_w  = (const float*)d_in[9];
  const float* fc1_b  = (const float*)d_in[10];
  const float* fc2_w  = (const float*)d_in[11];
  const float* fc2_b  = (const float*)d_in[12];
  const float* rel_t  = (const float*)d_in[13];
  const float* mask   = (const float*)d_in[15];
  (void)mask;

  char* ws = (char*)d_ws;
  unsigned short* qkv_wT  = (unsigned short*)(ws + 0);          // 576x192 bf16
  unsigned short* proj_wT = (unsigned short*)(ws + 221184);     // 192x192
  unsigned short* fc1_wT  = (unsigned short*)(ws + 294912);     // 768x192
  unsigned short* fc2_wT  = (unsigned short*)(ws + 589824);     // 192x768
  unsigned short* bufA    = (unsigned short*)(ws + 884736);     // 100352x192 bf16
  unsigned short* bufB    = (unsigned short*)(ws + 39419904ULL);// 100352x576/768 bf16
  float*          xres    = (float*)(ws + 193560576ULL);        // 100352x192 f32

  const int M = 100352;  // 32 * 56 * 56

  transpose_kernel<<<(192 * 576 + 255) / 256, 256, 0, stream>>>(qkv_w, qkv_wT, 192, 576);
  transpose_kernel<<<(192 * 192 + 255) / 256, 256, 0, stream>>>(proj_w, proj_wT, 192, 192);
  transpose_kernel<<<(192 * 768 + 255) / 256, 256, 0, stream>>>(fc1_w, fc1_wT, 192, 768);
  transpose_kernel<<<(768 * 192 + 255) / 256, 256, 0, stream>>>(fc2_w, fc2_wT, 768, 192);

  ln_kernel<<<M / 4, 256, 0, stream>>>(x, n1g, n1b, bufA);
  gemm_kernel<0><<<dim3(576 / 64, M / 128), 256, 0, stream>>>(bufA, qkv_wT, qkv_b, nullptr, bufB, 192, 576);
  attn_kernel<<<12288 / 2, 128, 0, stream>>>(bufB, rel_t, bufA);
  // fused proj + residual + LN2: writes xres (f32) and LN output in-place into bufA
  proj_ln_kernel<<<dim3(1, M / 128), 256, 0, stream>>>(bufA, proj_wT, proj_b, x, n2g, n2b, xres, bufA);
  gemm_kernel<2><<<dim3(768 / 64, M / 128), 256, 0, stream>>>(bufA, fc1_wT, fc1_b, nullptr, bufB, 192, 768);
  gemm_kernel<3><<<dim3(192 / 64, M / 128), 256, 0, stream>>>(bufB, fc2_wT, fc2_b, xres, d_out, 768, 192);
}

// Round 10
// 490.060 us; speedup vs baseline: 1.0560x; 1.0297x over previous
//
#include <hip/hip_runtime.h>

typedef __bf16 bf8 __attribute__((ext_vector_type(8)));
typedef float f4 __attribute__((ext_vector_type(4)));

// native bf16 store (compiler emits single-op converts; RNE)
__device__ __forceinline__ void stb(unsigned short* p, float v) { *(__bf16*)p = (__bf16)v; }

// async global->LDS, 16 bytes per lane; LDS dest = wave-uniform base + lane*16
__device__ __forceinline__ void gl_lds16(const unsigned short* g, unsigned short* l) {
  __builtin_amdgcn_global_load_lds((const __attribute__((address_space(1))) unsigned int*)g,
                                   (__attribute__((address_space(3))) unsigned int*)l,
                                   16, 0, 0);
}

// cheap GELU, exp2-folded constants + hardware rcp: 7 VALU incl. 2 transcendental.
// gelu(v) = v * rcp(1 + exp2(v*(-2.30222655 - 0.10294296 v^2)))
// |err| vs exact-erf GELU ~1e-3, below bf16 rounding; saturates correctly.
__device__ __forceinline__ float gelu_fast(float v) {
  float w = v * v;
  float u = v * (-2.30222655f - 0.10294296f * w);
  float e = __builtin_amdgcn_exp2f(u);
  return v * __builtin_amdgcn_rcpf(1.0f + e);
}

// ---------------- weight transpose+cast: f32 [K,N] -> bf16 [N,K] ----------------
__global__ void transpose_kernel(const float* __restrict__ in,
                                 unsigned short* __restrict__ out, int K, int N) {
  int idx = blockIdx.x * 256 + threadIdx.x;
  if (idx < K * N) {
    int n = idx / K, k = idx - n * K;
    stb(&out[idx], in[k * N + n]);
  }
}

// ---------------- LayerNorm: C=192, one wave per token, f32 in -> bf16 out ----------------
__global__ __launch_bounds__(256) void ln_kernel(const float* __restrict__ xin,
                                                 const float* __restrict__ g,
                                                 const float* __restrict__ bb,
                                                 unsigned short* __restrict__ out) {
  long token = (long)blockIdx.x * 4 + (threadIdx.x >> 6);
  int lane = threadIdx.x & 63;
  const float* row = xin + token * 192;
  float v[3] = {row[lane], row[lane + 64], row[lane + 128]};
  float s = v[0] + v[1] + v[2];
#pragma unroll
  for (int m = 1; m < 64; m <<= 1) s += __shfl_xor(s, m, 64);
  float mean = s * (1.0f / 192.0f);
  float d0 = v[0] - mean, d1 = v[1] - mean, d2 = v[2] - mean;
  float dd = d0 * d0 + d1 * d1 + d2 * d2;
#pragma unroll
  for (int m = 1; m < 64; m <<= 1) dd += __shfl_xor(dd, m, 64);
  float rstd = rsqrtf(dd * (1.0f / 192.0f) + 1e-5f);
  unsigned short* orow = out + token * 192;
#pragma unroll
  for (int i = 0; i < 3; i++) {
    int c = lane + i * 64;
    stb(&orow[c], (v[i] - mean) * rstd * g[c] + bb[c]);
  }
}

// ---------------- MFMA GEMM: out = A[M,K](bf16) @ Bt[N,K]^T(bf16) + bias(f32) ----------------
// BM=128, BN=64, BK=64, 256 threads (4 waves), double-buffered LDS,
// global_load_lds width-16 staging + XOR chunk swizzle, counted vmcnt(6),
// XCD-chunked tile remap (round-6 structure, best measured).
template <int EPI>
__global__ __launch_bounds__(256) void gemm_kernel(const unsigned short* __restrict__ A,
                                                   const unsigned short* __restrict__ Bt,
                                                   const float* __restrict__ bias,
                                                   const float* __restrict__ res,
                                                   void* __restrict__ out, int K, int N) {
  __shared__ __align__(16) unsigned short As[2][128 * 64];
  __shared__ __align__(16) unsigned short Bs[2][64 * 64];
  const int tid = threadIdx.x;
  const int wave = tid >> 6;
  const int lane = tid & 63;
  const int quad = lane >> 4;
  const int l16 = lane & 15;

  const int NX = gridDim.x;
  int lin = blockIdx.y * NX + blockIdx.x;
  const int T = NX * gridDim.y;
  if ((T & 7) == 0) {
    lin = (lin & 7) * (T >> 3) + (lin >> 3);
  }
  const int bx = lin % NX;
  const int by = lin / NX;
  const long m0 = (long)by * 128;
  const long n0 = (long)bx * 64;

  long a_src[4];
  int a_dstc[4];
#pragma unroll
  for (int j = 0; j < 4; ++j) {
    int L = (wave * 4 + j) * 64 + lane;
    int row = L >> 3, cs = L & 7;
    a_src[j] = (m0 + row) * (long)K + ((cs ^ (row & 7)) << 3);
    a_dstc[j] = (wave * 4 + j) * 512;
  }
  long b_src[2];
  int b_dstc[2];
#pragma unroll
  for (int j = 0; j < 2; ++j) {
    int L = (wave * 2 + j) * 64 + lane;
    int row = L >> 3, cs = L & 7;
    b_src[j] = (n0 + row) * (long)K + ((cs ^ (row & 7)) << 3);
    b_dstc[j] = (wave * 2 + j) * 512;
  }

  const int nT = K >> 6;
  f4 acc[2][4] = {};

#pragma unroll
  for (int j = 0; j < 4; ++j) gl_lds16(A + a_src[j], &As[0][a_dstc[j]]);
#pragma unroll
  for (int j = 0; j < 2; ++j) gl_lds16(Bt + b_src[j], &Bs[0][b_dstc[j]]);

  int cur = 0;
  for (int t = 0; t < nT; ++t) {
    if (t + 1 < nT) {
      const int k0 = (t + 1) << 6;
#pragma unroll
      for (int j = 0; j < 4; ++j) gl_lds16(A + a_src[j] + k0, &As[cur ^ 1][a_dstc[j]]);
#pragma unroll
      for (int j = 0; j < 2; ++j) gl_lds16(Bt + b_src[j] + k0, &Bs[cur ^ 1][b_dstc[j]]);
      asm volatile("s_waitcnt vmcnt(6)" ::: "memory");
    } else {
      asm volatile("s_waitcnt vmcnt(0)" ::: "memory");
    }
    __builtin_amdgcn_s_barrier();
    __builtin_amdgcn_sched_barrier(0);
#pragma unroll
    for (int kk = 0; kk < 2; ++kk) {
      bf8 a[2], b[4];
#pragma unroll
      for (int mt = 0; mt < 2; ++mt) {
        int r = wave * 32 + mt * 16 + l16;
        int c = kk * 4 + quad;
        a[mt] = *(const bf8*)&As[cur][r * 64 + ((c ^ (r & 7)) << 3)];
      }
#pragma unroll
      for (int nt = 0; nt < 4; ++nt) {
        int r = nt * 16 + l16;
        int c = kk * 4 + quad;
        b[nt] = *(const bf8*)&Bs[cur][r * 64 + ((c ^ (r & 7)) << 3)];
      }
#pragma unroll
      for (int mt = 0; mt < 2; ++mt)
#pragma unroll
        for (int nt = 0; nt < 4; ++nt)
          acc[mt][nt] = __builtin_amdgcn_mfma_f32_16x16x32_bf16(a[mt], b[nt], acc[mt][nt], 0, 0, 0);
    }
    __builtin_amdgcn_sched_barrier(0);
    __builtin_amdgcn_s_barrier();
    cur ^= 1;
  }

#pragma unroll
  for (int nt = 0; nt < 4; ++nt) {
    long n = n0 + nt * 16 + l16;
    float bv = bias[n];
#pragma unroll
    for (int mt = 0; mt < 2; ++mt) {
#pragma unroll
      for (int r = 0; r < 4; ++r) {
        long m = m0 + wave * 32 + mt * 16 + quad * 4 + r;
        float v = acc[mt][nt][r] + bv;
        long idx = m * N + n;
        if (EPI == 0) {
          stb(&((unsigned short*)out)[idx], v);
        } else if (EPI == 2) {
          stb(&((unsigned short*)out)[idx], gelu_fast(v));
        } else {
          ((float*)out)[idx] = v + res[idx];
        }
      }
    }
  }
}

// ---------------- fused proj GEMM + residual + LayerNorm2 ----------------
// BM=128, BN=192 (full row), BK=64, K=192, 256 threads (4 waves), grid (1, 784).
__global__ __launch_bounds__(256) void proj_ln_kernel(const unsigned short* __restrict__ A,
                                                      const unsigned short* __restrict__ Bt,
                                                      const float* __restrict__ bias,
                                                      const float* __restrict__ res,
                                                      const float* __restrict__ g2,
                                                      const float* __restrict__ b2,
                                                      float* __restrict__ xres,
                                                      unsigned short* __restrict__ lnout) {
  __shared__ __align__(16) unsigned short As[2][128 * 64];
  __shared__ __align__(16) unsigned short Bs[2][192 * 64];
  const int tid = threadIdx.x;
  const int wave = tid >> 6;
  const int lane = tid & 63;
  const int quad = lane >> 4;
  const int l16 = lane & 15;

  int lin = blockIdx.y;
  const int T = gridDim.y;
  if ((T & 7) == 0) lin = (lin & 7) * (T >> 3) + (lin >> 3);
  const long m0 = (long)lin * 128;

  long a_src[4];
  int a_dstc[4];
#pragma unroll
  for (int j = 0; j < 4; ++j) {
    int L = (wave * 4 + j) * 64 + lane;
    int row = L >> 3, cs = L & 7;
    a_src[j] = (m0 + row) * 192L + ((cs ^ (row & 7)) << 3);
    a_dstc[j] = (wave * 4 + j) * 512;
  }
  long b_src[6];
  int b_dstc[6];
#pragma unroll
  for (int j = 0; j < 6; ++j) {
    int L = (wave * 6 + j) * 64 + lane;
    int row = L >> 3, cs = L & 7;
    b_src[j] = row * 192L + ((cs ^ (row & 7)) << 3);
    b_dstc[j] = (wave * 6 + j) * 512;
  }

  f4 acc[2][12] = {};

#pragma unroll
  for (int j = 0; j < 4; ++j) gl_lds16(A + a_src[j], &As[0][a_dstc[j]]);
#pragma unroll
  for (int j = 0; j < 6; ++j) gl_lds16(Bt + b_src[j], &Bs[0][b_dstc[j]]);

  int cur = 0;
  for (int t = 0; t < 3; ++t) {
    if (t + 1 < 3) {
      const int k0 = (t + 1) << 6;
#pragma unroll
      for (int j = 0; j < 4; ++j) gl_lds16(A + a_src[j] + k0, &As[cur ^ 1][a_dstc[j]]);
#pragma unroll
      for (int j = 0; j < 6; ++j) gl_lds16(Bt + b_src[j] + k0, &Bs[cur ^ 1][b_dstc[j]]);
      asm volatile("s_waitcnt vmcnt(10)" ::: "memory");
    } else {
      asm volatile("s_waitcnt vmcnt(0)" ::: "memory");
    }
    __builtin_amdgcn_s_barrier();
    __builtin_amdgcn_sched_barrier(0);
#pragma unroll
    for (int kk = 0; kk < 2; ++kk) {
      bf8 a[2];
#pragma unroll
      for (int mt = 0; mt < 2; ++mt) {
        int r = wave * 32 + mt * 16 + l16;
        int c = kk * 4 + quad;
        a[mt] = *(const bf8*)&As[cur][r * 64 + ((c ^ (r & 7)) << 3)];
      }
#pragma unroll
      for (int nt = 0; nt < 12; ++nt) {
        int r = nt * 16 + l16;
        int c = kk * 4 + quad;
        bf8 b = *(const bf8*)&Bs[cur][r * 64 + ((c ^ (r & 7)) << 3)];
#pragma unroll
        for (int mt = 0; mt < 2; ++mt)
          acc[mt][nt] = __builtin_amdgcn_mfma_f32_16x16x32_bf16(a[mt], b, acc[mt][nt], 0, 0, 0);
      }
    }
    __builtin_amdgcn_sched_barrier(0);
    __builtin_amdgcn_s_barrier();
    cur ^= 1;
  }

#pragma unroll
  for (int mt = 0; mt < 2; ++mt) {
#pragma unroll
    for (int r = 0; r < 4; ++r) {
      long mm = m0 + wave * 32 + mt * 16 + quad * 4 + r;
      const float* rrow = res + mm * 192;
      float v[12];
      float s = 0.0f;
#pragma unroll
      for (int nt = 0; nt < 12; ++nt) {
        int n = nt * 16 + l16;
        float t = acc[mt][nt][r] + bias[n] + rrow[n];
        v[nt] = t;
        s += t;
      }
#pragma unroll
      for (int m = 1; m < 16; m <<= 1) s += __shfl_xor(s, m, 64);
      float mean = s * (1.0f / 192.0f);
      float d = 0.0f;
#pragma unroll
      for (int nt = 0; nt < 12; ++nt) {
        float dd = v[nt] - mean;
        d += dd * dd;
      }
#pragma unroll
      for (int m = 1; m < 16; m <<= 1) d += __shfl_xor(d, m, 64);
      float rstd = rsqrtf(d * (1.0f / 192.0f) + 1e-5f);
      float* xrow = xres + mm * 192;
      unsigned short* lrow = lnout + mm * 192;
#pragma unroll
      for (int nt = 0; nt < 12; ++nt) {
        int n = nt * 16 + l16;
        xrow[n] = v[nt];
        stb(&lrow[n], (v[nt] - mean) * rstd * g2[n] + b2[n]);
      }
    }
  }
}

// ---------------- fused MLP: out = gelu(A @ W1^T + b1) @ W2^T + b2 + xres ----------------
// 512 threads (8 waves), BM=128 (wave w owns rows [w*16, w*16+16)).
// 4 chunks of 192 fc1-columns; per chunk: fc1 partial (3 staged 64-K B1 tiles),
// GELU -> per-wave LDS G (stride 200 shorts: 16B-aligned, 2-way banks, no
// cross-wave sync needed), fc2 partial (3 staged B2 tiles) accumulating into
// the persistent 128x192 output acc. LDS: A 48K + B dbuf 48K + G 50K = 146 KB.
__global__ __launch_bounds__(512) void mlp_kernel(const unsigned short* __restrict__ A,    // LN2 out bf16 [M,192]
                                                  const unsigned short* __restrict__ W1t,  // [768,192] bf16
                                                  const unsigned short* __restrict__ W2t,  // [192,768] bf16
                                                  const float* __restrict__ b1,
                                                  const float* __restrict__ b2,
                                                  const float* __restrict__ res,           // xres f32 [M,192]
                                                  float* __restrict__ out) {               // [M,192] f32
  __shared__ __align__(16) unsigned short As[128 * 192];    // 48 KB
  __shared__ __align__(16) unsigned short Bs[2][192 * 64];  // 48 KB
  __shared__ __align__(16) unsigned short Gs[8][16 * 200];  // 50 KB
  const int tid = threadIdx.x;
  const int wave = tid >> 6;   // 0..7
  const int lane = tid & 63;
  const int quad = lane >> 4;
  const int l16 = lane & 15;

  int lin = blockIdx.x;
  const int T = gridDim.x;
  if ((T & 7) == 0) lin = (lin & 7) * (T >> 3) + (lin >> 3);
  const long m0 = (long)lin * 128;

  // ---- A staging: 128 rows x 24 chunks = 3072 chunks, 6 per thread ----
#pragma unroll
  for (int j = 0; j < 6; ++j) {
    int L = (wave * 6 + j) * 64 + lane;  // 0..3071
    int row = L / 24;
    int cs = L - row * 24;
    long src = (m0 + row) * 192L + ((cs ^ (row & 7)) << 3);
    gl_lds16(A + src, &As[(wave * 6 + j) * 512]);
  }

  // ---- B staging precompute: 192 rows x 8 chunks = 1536, 3 per thread ----
  int brow[3], bswz[3];
#pragma unroll
  for (int j = 0; j < 3; ++j) {
    int L = (wave * 3 + j) * 64 + lane;  // 0..1535
    brow[j] = L >> 3;
    int cs = L & 7;
    bswz[j] = ((cs ^ (brow[j] & 7)) << 3);
  }

  // stage B tile for (c, p, kb) into buf
#define STAGE_B(c_, p_, kb_, buf_)                                            \
  {                                                                           \
    _Pragma("unroll") for (int j = 0; j < 3; ++j) {                           \
      long src_;                                                              \
      if (p_ == 0)                                                            \
        src_ = (long)(c_) * 36864 + (long)brow[j] * 192 + (kb_) * 64 + bswz[j]; \
      else                                                                    \
        src_ = (long)brow[j] * 768 + (c_) * 192 + (kb_) * 64 + bswz[j];       \
      gl_lds16(((p_) == 0 ? W1t : W2t) + src_, &Bs[buf_][(wave * 3 + j) * 512]); \
    }                                                                         \
  }

  f4 oacc[12] = {};

  // prologue: stage 0 = (c=0, p=0, kb=0)
  STAGE_B(0, 0, 0, 0);

  int cur = 0;
  const int myrowA = (wave * 16 + l16) * 192;  // A-frag base (shorts)
  const int swzl = l16 & 7;
  unsigned short* Gmy = &Gs[wave][0];

#pragma unroll 1
  for (int c = 0; c < 4; ++c) {
    f4 gacc[12] = {};
    // ---- fc1 phase: 3 stages ----
#pragma unroll 1
    for (int kb = 0; kb < 3; ++kb) {
      // prefetch next stage
      if (kb < 2) {
        STAGE_B(c, 0, kb + 1, cur ^ 1);
      } else {
        STAGE_B(c, 1, 0, cur ^ 1);
      }
      asm volatile("s_waitcnt vmcnt(3)" ::: "memory");
      __builtin_amdgcn_s_barrier();
      __builtin_amdgcn_sched_barrier(0);
#pragma unroll
      for (int kk = 0; kk < 2; ++kk) {
        int csr = (kb * 2 + kk) * 4 + quad;
        bf8 a = *(const bf8*)&As[myrowA + ((csr ^ swzl) << 3)];
#pragma unroll
        for (int nt = 0; nt < 12; ++nt) {
          bf8 b = *(const bf8*)&Bs[cur][(nt * 16 + l16) * 64 + (((kk * 4 + quad) ^ swzl) << 3)];
          gacc[nt] = __builtin_amdgcn_mfma_f32_16x16x32_bf16(a, b, gacc[nt], 0, 0, 0);
        }
      }
      __builtin_amdgcn_sched_barrier(0);
      __builtin_amdgcn_s_barrier();
      cur ^= 1;
    }
    // ---- GELU -> per-wave G (no cross-wave sync needed) ----
#pragma unroll
    for (int nt = 0; nt < 12; ++nt) {
      float bv = b1[c * 192 + nt * 16 + l16];
#pragma unroll
      for (int r = 0; r < 4; ++r) {
        float g = gelu_fast(gacc[nt][r] + bv);
        stb(&Gmy[(quad * 4 + r) * 200 + nt * 16 + l16], g);
      }
    }
    asm volatile("s_waitcnt lgkmcnt(0)" ::: "memory");
    __builtin_amdgcn_sched_barrier(0);
    // ---- fc2 phase: 3 stages ----
#pragma unroll 1
    for (int kb = 0; kb < 3; ++kb) {
      if (kb < 2) {
        STAGE_B(c, 1, kb + 1, cur ^ 1);
        asm volatile("s_waitcnt vmcnt(3)" ::: "memory");
      } else if (c < 3) {
        STAGE_B(c + 1, 0, 0, cur ^ 1);
        asm volatile("s_waitcnt vmcnt(3)" ::: "memory");
      } else {
        asm volatile("s_waitcnt vmcnt(0)" ::: "memory");
      }
      __builtin_amdgcn_s_barrier();
      __builtin_amdgcn_sched_barrier(0);
#pragma unroll
      for (int kk = 0; kk < 2; ++kk) {
        bf8 a = *(const bf8*)&Gmy[l16 * 200 + (kb * 2 + kk) * 32 + quad * 8];
#pragma unroll
        for (int nt = 0; nt < 12; ++nt) {
          bf8 b = *(const bf8*)&Bs[cur][(nt * 16 + l16) * 64 + (((kk * 4 + quad) ^ swzl) << 3)];
          oacc[nt] = __builtin_amdgcn_mfma_f32_16x16x32_bf16(a, b, oacc[nt], 0, 0, 0);
        }
      }
      __builtin_amdgcn_sched_barrier(0);
      __builtin_amdgcn_s_barrier();
      cur ^= 1;
    }
  }
#undef STAGE_B

  // ---- epilogue: + b2 + xres -> f32 out ----
#pragma unroll
  for (int r = 0; r < 4; ++r) {
    long mm = m0 + wave * 16 + quad * 4 + r;
    const float* rrow = res + mm * 192;
    float* orow = out + mm * 192;
#pragma unroll
    for (int nt = 0; nt < 12; ++nt) {
      int n = nt * 16 + l16;
      orow[n] = oacc[nt][r] + b2[n] + rrow[n];
    }
  }
}

// ---------------- MFMA shifted-window attention ----------------
__global__ __launch_bounds__(128) void attn_kernel(const unsigned short* __restrict__ qkv,
                                                   const float* __restrict__ rel_t,
                                                   unsigned short* __restrict__ o) {
  __shared__ __align__(16) unsigned short sh[2 * 6912];
  __shared__ float relh[2][170];
  __shared__ int toksh[2][49];
  __shared__ int zsh[2][49];
  const int wave = threadIdx.x >> 6;
  const int lane = threadIdx.x & 63;
  const int quad = lane >> 4;
  const int l16 = lane & 15;
  const int p = blockIdx.x * 2 + wave;
  const int head = p % 6;
  const int wib = p / 6;
  const int wi = wib & 63;
  const int b = wib >> 6;
  unsigned short* Vts = sh + wave * 6912;
  unsigned short* Ps = Vts + 2304;

  if (lane < 49) {
    int r = lane / 7, c = lane - (lane / 7) * 7;
    int ph = (wi >> 3) * 7 + r, pw = (wi & 7) * 7 + c;
    int h = ph + 3; if (h >= 56) h -= 56;
    int w = pw + 3; if (w >= 56) w -= 56;
    toksh[wave][lane] = (b * 56 + h) * 56 + w;
    int zh = (ph < 49) ? 0 : (ph < 53 ? 1 : 2);
    int zw = (pw < 49) ? 0 : (pw < 53 ? 1 : 2);
    zsh[wave][lane] = zh * 3 + zw;
  }
  for (int i = lane; i < 169; i += 64) relh[wave][i] = rel_t[i * 6 + head];
  {
#pragma unroll
    for (int e = 0; e < 4; e++) {
      int ee = lane + e * 64;
      int d = ee >> 3, c8 = ee & 7;
      *(unsigned int*)&Vts[d * 72 + 48 + c8 * 2] = 0u;
    }
  }
  __syncthreads();

  for (int e = lane; e < 196; e += 64) {
    int n = e >> 2, c = e & 3;
    int t = toksh[wave][n];
    uint4 vc = *(const uint4*)(qkv + (long)t * 576 + head * 32 + 384 + c * 8);
    const unsigned short* vv = (const unsigned short*)&vc;
#pragma unroll
    for (int j = 0; j < 8; j++) Vts[(c * 8 + j) * 72 + n] = vv[j];
  }

  bf8 zv;
#pragma unroll
  for (int q8 = 0; q8 < 8; q8++) zv[q8] = (__bf16)0.0f;
  bf8 af[4], bf_[4];
#pragma unroll
  for (int i = 0; i < 4; i++) {
    int row = 16 * i + l16;
    int rv = row < 49 ? row : 48;
    long base = (long)toksh[wave][rv] * 576 + head * 32 + quad * 8;
    bf8 qf = *(const bf8*)(qkv + base);
    bf8 kf = *(const bf8*)(qkv + base + 192);
    if (row >= 49) { qf = zv; kf = zv; }
    af[i] = qf;
    bf_[i] = kf;
  }

  f4 S[4][4];
#pragma unroll
  for (int i = 0; i < 4; i++)
#pragma unroll
    for (int j = 0; j < 4; j++)
      S[i][j] = __builtin_amdgcn_mfma_f32_16x16x32_bf16(af[i], bf_[j], (f4){0.f, 0.f, 0.f, 0.f}, 0, 0, 0);

  int colv[4], colkey[4], zcol[4];
#pragma unroll
  for (int jt = 0; jt < 4; jt++) {
    int col = 16 * jt + l16;
    int cc = col < 49 ? col : 48;
    int rj = cc / 7, cj = cc - rj * 7;
    colkey[jt] = rj * 13 + cj;
    zcol[jt] = zsh[wave][cc];
    colv[jt] = (col < 49);
  }

  __syncthreads();

  const float sc = 0.17677669529663687f;  // 1/sqrt(32)
#pragma unroll
  for (int it = 0; it < 4; it++) {
#pragma unroll
    for (int r = 0; r < 4; r++) {
      int row = 16 * it + quad * 4 + r;
      int row2 = row < 49 ? row : 48;
      int ri = row2 / 7, ci = row2 - ri * 7;
      int rk = ri * 13 + ci + 84;
      int zr = zsh[wave][row2];
      float v[4];
#pragma unroll
      for (int jt = 0; jt < 4; jt++) {
        float bias = relh[wave][rk - colkey[jt]];
        float msk = (zr == zcol[jt]) ? 0.0f : -100.0f;
        float val = S[it][jt][r] * sc + bias + msk;
        v[jt] = colv[jt] ? val : -1e30f;
      }
      float mx = fmaxf(fmaxf(v[0], v[1]), fmaxf(v[2], v[3]));
#pragma unroll
      for (int m = 1; m < 16; m <<= 1) mx = fmaxf(mx, __shfl_xor(mx, m, 64));
      float e0 = __expf(v[0] - mx), e1 = __expf(v[1] - mx), e2 = __expf(v[2] - mx), e3 = __expf(v[3] - mx);
      float sum = e0 + e1 + e2 + e3;
#pragma unroll
      for (int m = 1; m < 16; m <<= 1) sum += __shfl_xor(sum, m, 64);
      float inv = 1.0f / sum;
      stb(&Ps[row * 72 + 0 + l16], e0 * inv);
      stb(&Ps[row * 72 + 16 + l16], e1 * inv);
      stb(&Ps[row * 72 + 32 + l16], e2 * inv);
      stb(&Ps[row * 72 + 48 + l16], e3 * inv);
    }
  }
  __syncthreads();

  f4 O[4][2] = {};
#pragma unroll
  for (int ks = 0; ks < 2; ks++) {
    bf8 pv[2];
#pragma unroll
    for (int nt = 0; nt < 2; nt++) pv[nt] = *(const bf8*)&Vts[(16 * nt + l16) * 72 + ks * 32 + quad * 8];
#pragma unroll
    for (int mt = 0; mt < 4; mt++) {
      bf8 pa = *(const bf8*)&Ps[(16 * mt + l16) * 72 + ks * 32 + quad * 8];
#pragma unroll
      for (int nt = 0; nt < 2; nt++)
        O[mt][nt] = __builtin_amdgcn_mfma_f32_16x16x32_bf16(pa, pv[nt], O[mt][nt], 0, 0, 0);
    }
  }
#pragma unroll
  for (int mt = 0; mt < 4; mt++) {
#pragma unroll
    for (int r = 0; r < 4; r++) {
      int row = 16 * mt + quad * 4 + r;
      if (row < 49) {
        long base = (long)toksh[wave][row] * 192 + head * 32 + l16;
        stb(&o[base], O[mt][0][r]);
        stb(&o[base + 16], O[mt][1][r]);
      }
    }
  }
}

extern "C" void kernel_launch(void* const* d_in, const int* in_sizes, int n_in,
                              void* d_out, int out_size, void* d_ws, size_t ws_size,
                              hipStream_t stream) {
  const float* x      = (const float*)d_in[0];
  const float* n1g    = (const float*)d_in[1];
  const float* n1b    = (const float*)d_in[2];
  const float* qkv_w  = (const float*)d_in[3];
  const float* qkv_b  = (const float*)d_in[4];
  const float* proj_w = (const float*)d_in[5];
  const float* proj_b = (const float*)d_in[6];
  const float* n2g    = (const float*)d_in[7];
  const float* n2b    = (const float*)d_in[8];
  const float* fc1_w  = (const float*)d_in[9];
  const float* fc1_b  = (const float*)d_in[10];
  const float* fc2_w  = (const float*)d_in[11];
  const float* fc2_b  = (const float*)d_in[12];
  const float* rel_t  = (const float*)d_in[13];
  const float* mask   = (const float*)d_in[15];
  (void)mask;

  char* ws = (char*)d_ws;
  unsigned short* qkv_wT  = (unsigned short*)(ws + 0);          // 576x192 bf16
  unsigned short* proj_wT = (unsigned short*)(ws + 221184);     // 192x192
  unsigned short* fc1_wT  = (unsigned short*)(ws + 294912);     // 768x192
  unsigned short* fc2_wT  = (unsigned short*)(ws + 589824);     // 192x768
  unsigned short* bufA    = (unsigned short*)(ws + 884736);     // 100352x192 bf16
  unsigned short* bufB    = (unsigned short*)(ws + 39419904ULL);// 100352x576 bf16
  float*          xres    = (float*)(ws + 193560576ULL);        // 100352x192 f32

  const int M = 100352;  // 32 * 56 * 56

  transpose_kernel<<<(192 * 576 + 255) / 256, 256, 0, stream>>>(qkv_w, qkv_wT, 192, 576);
  transpose_kernel<<<(192 * 192 + 255) / 256, 256, 0, stream>>>(proj_w, proj_wT, 192, 192);
  transpose_kernel<<<(192 * 768 + 255) / 256, 256, 0, stream>>>(fc1_w, fc1_wT, 192, 768);
  transpose_kernel<<<(768 * 192 + 255) / 256, 256, 0, stream>>>(fc2_w, fc2_wT, 768, 192);

  ln_kernel<<<M / 4, 256, 0, stream>>>(x, n1g, n1b, bufA);
  gemm_kernel<0><<<dim3(576 / 64, M / 128), 256, 0, stream>>>(bufA, qkv_wT, qkv_b, nullptr, bufB, 192, 576);
  attn_kernel<<<12288 / 2, 128, 0, stream>>>(bufB, rel_t, bufA);
  proj_ln_kernel<<<dim3(1, M / 128), 256, 0, stream>>>(bufA, proj_wT, proj_b, x, n2g, n2b, xres, bufA);
  mlp_kernel<<<M / 128, 512, 0, stream>>>(bufA, fc1_wT, fc2_wT, fc1_b, fc2_b, xres, (float*)d_out);
}